// Round 9
// baseline (68.774 us; speedup 1.0000x reference)
//
#include <hip/hip_runtime.h>
#include <hip/hip_bf16.h>

constexpr int KNB = 16;  // neighbors
constexpr int HH  = 4;   // heads
constexpr int DD  = 32;  // head dim
constexpr int NPB = 16;  // nodes per block

typedef __attribute__((ext_vector_type(4))) float f32x4;
typedef __attribute__((ext_vector_type(8))) short bf16x8;
union BFRAG { bf16x8 v; unsigned u[4]; };

// float offsets inside one LDS node-buffer
constexpr int L_K  = 0;     // 2048 floats: k, fragment-ordered [h][p][lane]
constexpr int L_V  = 2048;  // 2048 floats: v, transposed [r][t][h][lg][lm]
constexpr int L_G  = 4096;  // 512  floats: geo, fragment-ordered [p][lane]
constexpr int L_Q  = 4608;  // 256  floats: q, linear (duplicated halves)
constexpr int L_SZ = 4864;  // 19456 B per buffer

__device__ __forceinline__ unsigned pk_bf16(float a, float b) {
    union { __hip_bfloat162 b2; unsigned u; } r;
    r.b2 = __float22bfloat162_rn(make_float2(a, b));
    return r.u;
}
__device__ __forceinline__ float2 unpk_bf16(unsigned u) {
    union { unsigned u; __hip_bfloat162 b2; } r; r.u = u;
    return make_float2(__bfloat162float(r.b2.x), __bfloat162float(r.b2.y));
}
// async global->LDS DMA, 16B per lane; dst = wave-uniform base + lane*16
__device__ __forceinline__ void gload16(const float* g, float* l) {
    __builtin_amdgcn_global_load_lds(
        (const __attribute__((address_space(1))) unsigned*)g,
        (__attribute__((address_space(3))) unsigned*)l, 16, 0, 0);
}

// 4 waves/block = 4 heads of one node per iteration; double-buffered LDS
// staging via global_load_lds with counted s_waitcnt vmcnt(6) (never 0):
// node t+1's 6 DMA loads stay in flight while node t computes. LDS layouts
// are permuted at stage time through per-lane SOURCE addresses (dest is
// linear), making every ds_read conflict-free. Compute per wave = R7's
// verified per-head math: hi/lo bf16 MFMA Linear (fp32-level accuracy,
// sqrt(32) folded into W, bias in MFMA C-init), shuffle LN over e,
// max-free softmax over k (shift-invariant, post-LN |z|<=~5.6).
__global__ __launch_bounds__(256, 4) void geoneigh_pipe(
    const float* __restrict__ q, const float* __restrict__ kn,
    const float* __restrict__ vn, const float* __restrict__ geo,
    const float* __restrict__ W, const float* __restrict__ bvec,
    const float* __restrict__ gamma, const float* __restrict__ beta,
    float* __restrict__ out, int BN)
{
    __shared__ __align__(16) float lds[2][L_SZ];

    const int tid = threadIdx.x;
    const int l   = tid & 63;
    const int wv  = tid >> 6;    // wave id == head id == staged v-row id
    const int lm  = l & 15;      // edge (A/C row) / e-low (B col)
    const int lg  = l >> 4;      // k-group (A/B) / edge-block (C)

    const float SC    = 5.656854249492381f;   // sqrt(32), folded into W
    const float LOG2E = 1.4426950408889634f;  // folded into gamma/beta

    // ---- once per block-lifetime: B operand (SC*W) hi/lo bf16 ----
    BFRAG Wh[2], Wl[2];
    #pragma unroll
    for (int t = 0; t < 2; ++t) {
        const float* wr = &W[(t * 16 + lm) * DD + lg * 8];
        const float4 wa = *(const float4*)wr;
        const float4 wb = *(const float4*)(wr + 4);
        float wf[8] = {wa.x * SC, wa.y * SC, wa.z * SC, wa.w * SC,
                       wb.x * SC, wb.y * SC, wb.z * SC, wb.w * SC};
        #pragma unroll
        for (int p = 0; p < 4; ++p) {
            const unsigned h = pk_bf16(wf[2 * p], wf[2 * p + 1]);
            const float2 hr = unpk_bf16(h);
            Wh[t].u[p] = h;
            Wl[t].u[p] = pk_bf16(wf[2 * p] - hr.x, wf[2 * p + 1] - hr.y);
        }
    }
    float bias[2], gamL[2], betL[2];
    #pragma unroll
    for (int t = 0; t < 2; ++t) {
        bias[t] = bvec[lm + 16 * t];
        gamL[t] = gamma[lm + 16 * t] * LOG2E;
        betL[t] = beta[lm + 16 * t] * LOG2E;
    }

    // ---- per-lane stage SOURCE offsets (floats), loop-invariant ----
    // k chunks (head wv, p=0/1): lds[h][p][lane] <- k[edge=lm][h][d=lg*8+p*4..]
    // k edge stride = HH*DD = 128 floats
    const int koff0 = lm * 128 + wv * 32 + lg * 8;
    // v chunks (row r=wv, t=0/1): lds[r][t][h=lg][lgv][lm0..] <-
    //   v[edge=lgv*4+r][h][e=lm0+16t..], lgv=(l>>2)&3, lm0=(l&3)*4
    const int vbase = (((l >> 2) & 3) * 4 + wv) * 128 + lg * 32 + (l & 3) * 4;
    // geo chunk (p=wv&1): lds[p][lane] <- geo[edge=lm][d=lg*8+p*4..]
    // geo edge stride = DD = 32 floats  (R8 bug was lm*128 here -> OOB fault)
    const int goff  = lm * 32 + lg * 8 + (wv & 1) * 4;
    const int qoff  = (l & 31) * 4;  // linear copy, lanes 32-63 duplicate
    // wave-uniform LDS dst offsets (floats)
    const int dK = L_K + 2 * wv * 256;
    const int dV = L_V + 2 * wv * 256;
    const int dG = L_G + (wv & 1) * 256;

    const int nbase = blockIdx.x * NPB;
    const int nmax  = BN - 1;

    auto stage = [&](int buf, int n) {   // exactly 6 DMA loads per wave
        const float* kN = kn  + (size_t)n * (KNB * HH * DD);
        const float* vN = vn  + (size_t)n * (KNB * HH * DD);
        const float* gN = geo + (size_t)n * (KNB * DD);
        const float* qN = q   + (size_t)n * (HH * DD);
        float* B = &lds[buf][0];
        gload16(kN + koff0,      B + dK);
        gload16(kN + koff0 + 4,  B + dK + 256);
        gload16(vN + vbase,      B + dV);
        gload16(vN + vbase + 16, B + dV + 256);
        gload16(gN + goff,       B + dG);
        gload16(qN + qoff,       B + L_Q);
    };
    auto cnode = [&](int t) { int n = nbase + t; return n > nmax ? nmax : n; };

    stage(0, cnode(0));

    #pragma unroll 2
    for (int t = 0; t < NPB; ++t) {
        stage((t + 1) & 1, cnode(t + 1));          // prefetch next node
        asm volatile("s_waitcnt vmcnt(6)" ::: "memory");  // node t landed
        __builtin_amdgcn_s_barrier();
        __builtin_amdgcn_sched_barrier(0);

        const float* B = &lds[t & 1][0];
        const int n = cnode(t);

        // ---- fragment reads from LDS (conflict-free by layout) ----
        const f32x4 kf0 = *(const f32x4*)(B + L_K + wv * 512 + l * 4);
        const f32x4 kf1 = *(const f32x4*)(B + L_K + wv * 512 + 256 + l * 4);
        const f32x4 gf0 = *(const f32x4*)(B + L_G + l * 4);
        const f32x4 gf1 = *(const f32x4*)(B + L_G + 256 + l * 4);
        const f32x4 qf0 = *(const f32x4*)(B + L_Q + wv * 32 + lg * 8);
        const f32x4 qf1 = *(const f32x4*)(B + L_Q + wv * 32 + lg * 8 + 4);
        float vr[2][4];
        #pragma unroll
        for (int t2 = 0; t2 < 2; ++t2)
            #pragma unroll
            for (int r = 0; r < 4; ++r)
                vr[t2][r] = B[L_V + (r * 32 + t2 * 16 + wv * 4 + lg) * 16 + lm];

        // ---- w = q - k + geo; hi/lo bf16 split; MFMA ----
        float wvv[8];
        #pragma unroll
        for (int j = 0; j < 4; ++j) {
            wvv[j]     = qf0[j] - kf0[j] + gf0[j];
            wvv[4 + j] = qf1[j] - kf1[j] + gf1[j];
        }
        BFRAG Ah, Al;
        #pragma unroll
        for (int p = 0; p < 4; ++p) {
            const unsigned h = pk_bf16(wvv[2 * p], wvv[2 * p + 1]);
            const float2 hr = unpk_bf16(h);
            Ah.u[p] = h;
            Al.u[p] = pk_bf16(wvv[2 * p] - hr.x, wvv[2 * p + 1] - hr.y);
        }
        f32x4 acc[2];
        #pragma unroll
        for (int t2 = 0; t2 < 2; ++t2) {
            f32x4 c = {bias[t2], bias[t2], bias[t2], bias[t2]};
            c = __builtin_amdgcn_mfma_f32_16x16x32_bf16(Ah.v, Wh[t2].v, c, 0, 0, 0);
            c = __builtin_amdgcn_mfma_f32_16x16x32_bf16(Ah.v, Wl[t2].v, c, 0, 0, 0);
            c = __builtin_amdgcn_mfma_f32_16x16x32_bf16(Al.v, Wh[t2].v, c, 0, 0, 0);
            acc[t2] = c;
        }

        // ---- ReLU + LN (over e), softmax-no-max (over k), PV ----
        // C layout: lane holds C[edge=lg*4+r][e=lm+16*t2]
        float x[2][4], t1[4], t2s[4];
        #pragma unroll
        for (int t2 = 0; t2 < 2; ++t2)
            #pragma unroll
            for (int r = 0; r < 4; ++r)
                x[t2][r] = fmaxf(acc[t2][r], 0.f);
        #pragma unroll
        for (int r = 0; r < 4; ++r) {
            t1[r]  = x[0][r] + x[1][r];
            t2s[r] = x[0][r] * x[0][r] + x[1][r] * x[1][r];
        }
        #pragma unroll
        for (int m = 1; m <= 8; m <<= 1) {
            #pragma unroll
            for (int r = 0; r < 4; ++r) {
                t1[r]  += __shfl_xor(t1[r], m);
                t2s[r] += __shfl_xor(t2s[r], m);
            }
        }
        float z[2][4];
        #pragma unroll
        for (int r = 0; r < 4; ++r) {
            const float mu  = t1[r] * 0.03125f;
            const float var = fmaxf(t2s[r] * 0.03125f - mu * mu, 0.f);
            const float inv = rsqrtf(var + 1e-5f);
            #pragma unroll
            for (int t2 = 0; t2 < 2; ++t2)
                z[t2][r] = (x[t2][r] - mu) * inv * gamL[t2] + betL[t2];
        }
        float S[2], o[2];
        #pragma unroll
        for (int t2 = 0; t2 < 2; ++t2) {
            float s = 0.f, oo = 0.f;
            #pragma unroll
            for (int r = 0; r < 4; ++r) {
                const float p = exp2f(z[t2][r]);  // e^orig (log2e folded)
                s += p;
                oo = fmaf(p, vr[t2][r], oo);
            }
            s  += __shfl_xor(s, 16);
            s  += __shfl_xor(s, 32);
            oo += __shfl_xor(oo, 16);
            oo += __shfl_xor(oo, 32);
            S[t2] = s; o[t2] = oo;
        }
        if (l < 32) {
            const int sel = (l >> 4) & 1;       // e bit4
            const float oo = sel ? o[1] : o[0];
            const float ss = sel ? S[1] : S[0];
            out[((size_t)n * HH + wv) * DD + l] = __fdividef(oo, ss);
        }

        asm volatile("s_waitcnt lgkmcnt(0)" ::: "memory");  // LDS reads done
        __builtin_amdgcn_s_barrier();   // buf[t&1] may now be overwritten
    }
}

extern "C" void kernel_launch(void* const* d_in, const int* in_sizes, int n_in,
                              void* d_out, int out_size, void* d_ws, size_t ws_size,
                              hipStream_t stream) {
    const float* q   = (const float*)d_in[0];
    const float* kn  = (const float*)d_in[1];
    const float* vn  = (const float*)d_in[2];
    const float* geo = (const float*)d_in[3];
    const float* W   = (const float*)d_in[4];
    const float* b   = (const float*)d_in[5];
    const float* gam = (const float*)d_in[6];
    const float* bet = (const float*)d_in[7];
    float* out = (float*)d_out;

    const int BN     = in_sizes[0] / (HH * DD);   // B*N nodes
    const int blocks = (BN + NPB - 1) / NPB;

    hipLaunchKernelGGL(geoneigh_pipe, dim3(blocks), dim3(256), 0, stream,
                       q, kn, vn, geo, W, b, gam, bet, out, BN);
}